// Round 4
// baseline (99.653 us; speedup 1.0000x reference)
//
#include <hip/hip_runtime.h>

// S1Net: 500k Izhikevich neurons, 8 input connections, 200 sim steps.
// Key trick: input current I = round(input_n*20) takes only 21 integer values,
// so the 200-step sim is a 21-entry LUT computed per-block (hidden under loads).
// Resubmission (4th): broker GPUAcquisitionTimeout in all prior rounds; no
// counters exist to act on, so the theory-checked candidate is unchanged.

namespace {

constexpr int N    = 500000;
constexpr int NT4  = N / 4;                    // 125000 threads, 4 neurons each
constexpr int BLK  = 256;
constexpr int NBLK = (NT4 + BLK - 1) / BLK;    // 489

// XLA/Eigen f32 tanh rational approximation, evaluated without FMA
// contraction to track the reference's elementwise emitter as closely
// as possible (matters at the input_n >= 0.5 and round(.) thresholds).
__device__ __forceinline__ float xla_tanh(float x) {
  float xc = fminf(fmaxf(x, -9.0f), 9.0f);
  float x2 = __fmul_rn(xc, xc);
  float p = -2.76076847742355e-16f;
  p = __fadd_rn(__fmul_rn(p, x2), 2.00018790482477e-13f);
  p = __fadd_rn(__fmul_rn(p, x2), -8.60467152213735e-11f);
  p = __fadd_rn(__fmul_rn(p, x2), 5.12229709037114e-08f);
  p = __fadd_rn(__fmul_rn(p, x2), 1.48572235717979e-05f);
  p = __fadd_rn(__fmul_rn(p, x2), 6.37261928875436e-04f);
  p = __fadd_rn(__fmul_rn(p, x2), 4.89352455891786e-03f);
  p = __fmul_rn(xc, p);
  float q = 1.19825839466702e-06f;
  q = __fadd_rn(__fmul_rn(q, x2), 1.18534705686654e-04f);
  q = __fadd_rn(__fmul_rn(q, x2), 2.26843463243900e-03f);
  q = __fadd_rn(__fmul_rn(q, x2), 4.89352518554385e-03f);
  float r = p / q;
  return (fabsf(x) < 0.0004f) ? x : r;
}

__global__ void __launch_bounds__(BLK) kA(const float* __restrict__ inp,
                                          const float* __restrict__ FR,
                                          const float* __restrict__ C,
                                          const float* __restrict__ W,
                                          float* __restrict__ out,
                                          unsigned int* __restrict__ flag) {
  __shared__ float lut[24];  // spike_count/200 for I = 0..20
  const int tid = threadIdx.x;
  const int gid = blockIdx.x * BLK + tid;
  const bool active = gid < NT4;
  const int src = active ? gid : 0;  // clamp so tail threads load safely

  // Issue all global loads first so they are in flight during the sim.
  float4 in4 = reinterpret_cast<const float4*>(inp)[src];
  float4 c4  = reinterpret_cast<const float4*>(C)[src];
  float fa[8][4], wa[8][4];
#pragma unroll
  for (int k = 0; k < 8; ++k) {
    float4 fv = reinterpret_cast<const float4*>(FR + (size_t)k * N)[src];
    float4 wv = reinterpret_cast<const float4*>(W + (size_t)k * N)[src];
    fa[k][0] = fv.x; fa[k][1] = fv.y; fa[k][2] = fv.z; fa[k][3] = fv.w;
    wa[k][0] = wv.x; wa[k][1] = wv.y; wa[k][2] = wv.z; wa[k][3] = wv.w;
  }

  // 21 Izhikevich sims (I = 0..20) on lanes 0..20 of wave 0.
  // Dependency-chain latency (~2.7us) overlaps the HBM load phase across
  // the ~2 concurrent blocks/CU.
  if (tid < 21) {
    const float I = (float)tid;
    float mem = -70.0f, u = -14.0f, acc = 0.0f;
#pragma unroll 10
    for (int t = 0; t < 200; ++t) {
      float dm = (0.04f * mem) * mem + 5.0f * mem;  // reference assoc order
      dm = dm + 140.0f;
      dm = dm - u;
      dm = dm + I;
      mem = mem + 0.5f * dm;                 // DT = 0.5
      u = u + 0.01f * (0.2f * mem - u);      // DT*A = 0.01, uses NEW mem
      const bool sp = mem >= 30.0f;
      acc += sp ? 1.0f : 0.0f;
      mem = sp ? -65.0f : mem;               // C_RESET
      u = sp ? u + 8.0f : u;                 // D
    }
    lut[tid] = acc / 200.0f;                 // FR_n for this I
  }
  __syncthreads();

  if (!active) return;

  // FR_W dot product: sequential add order, no contraction.
  float frw[4];
#pragma unroll
  for (int j = 0; j < 4; ++j) {
    float s = __fmul_rn(fa[0][j], wa[0][j]);
#pragma unroll
    for (int k = 1; k < 8; ++k)
      s = __fadd_rn(s, __fmul_rn(fa[k][j], wa[k][j]));
    frw[j] = s;
  }

  const float iv[4] = {in4.x, in4.y, in4.z, in4.w};
  const float cv[4] = {c4.x, c4.y, c4.z, c4.w};
  float fr_n[4], in_n[4];
  bool s_any = false;
#pragma unroll
  for (int j = 0; j < 4; ++j) {
    float sf = fmaxf(xla_tanh(frw[j]), 0.0f);
    float d  = __fsub_rn(iv[j], sf);
    float v  = __fadd_rn(__fmul_rn(-cv[j], d), iv[j]);  // -C*(input-sf)+input
    float n  = fmaxf(v, 0.0f);
    in_n[j] = n;
    int ir = (int)rintf(__fmul_rn(n, 20.0f));           // RNE == jnp.round
    ir = ir < 0 ? 0 : (ir > 20 ? 20 : ir);
    fr_n[j] = lut[ir];
    s_any |= (n >= 0.5f);
  }

  float4 o0 = {fr_n[0], fr_n[1], fr_n[2], fr_n[3]};
  float4 o1 = {in_n[0], in_n[1], in_n[2], in_n[3]};
  reinterpret_cast<float4*>(out)[gid] = o0;           // FR_n
  reinterpret_cast<float4*>(out + N)[gid] = o1;       // input_n

  // fired_any: one plain store per wave that saw a spike (same value, benign race)
  unsigned long long b = __ballot(s_any);
  if (b != 0ULL && (int)(tid & 63) == (__ffsll((unsigned long long)b) - 1))
    *flag = 1u;
}

__global__ void __launch_bounds__(BLK) kB(const float* __restrict__ WLi,
                                          const float* __restrict__ Fired,
                                          const unsigned int* __restrict__ flag,
                                          float* __restrict__ out) {
  const int gid = blockIdx.x * BLK + threadIdx.x;
  const float fired_any = (*flag != 0u) ? 1.0f : 0.0f;
  const float fired_new = __fadd_rn(Fired[0], fired_any);
  if (gid == 0) out[2 * N] = fired_new;
  if (gid >= NT4) return;

  float4 wl4 = reinterpret_cast<const float4*>(WLi)[gid];
  float4 in4 = reinterpret_cast<const float4*>(out + N)[gid];  // input_n from kA
  const float wv[4] = {wl4.x, wl4.y, wl4.z, wl4.w};
  const float nv[4] = {in4.x, in4.y, in4.z, in4.w};
  float res[4];

  if (fired_any > 0.0f) {
    const float e = expf(fired_new);
#pragma unroll
    for (int j = 0; j < 4; ++j) {
      // 2*arccos(S): S=1 -> 0, S=0 -> pi (f32)
      float two_acos = (nv[j] >= 0.5f) ? 0.0f : 3.14159274101257324f;
      float t = __fmul_rn(two_acos, e);
      float x = __fsub_rn(wv[j], t);
      x = __fsub_rn(x, 1.0f);
      res[j] = __fadd_rn(xla_tanh(x), 1.0f);
    }
  } else {
#pragma unroll
    for (int j = 0; j < 4; ++j) res[j] = wv[j];
  }

  float* dst = out + 2 * N + 1 + (size_t)gid * 4;  // 2N+1 start: scalar stores
  dst[0] = res[0]; dst[1] = res[1]; dst[2] = res[2]; dst[3] = res[3];
}

}  // namespace

extern "C" void kernel_launch(void* const* d_in, const int* in_sizes, int n_in,
                              void* d_out, int out_size, void* d_ws, size_t ws_size,
                              hipStream_t stream) {
  const float* inp   = (const float*)d_in[0];
  const float* FR    = (const float*)d_in[1];
  const float* C     = (const float*)d_in[2];
  const float* Fired = (const float*)d_in[3];
  const float* WLi   = (const float*)d_in[4];
  const float* W     = (const float*)d_in[5];
  float* out = (float*)d_out;
  unsigned int* flag = (unsigned int*)d_ws;

  hipMemsetAsync(flag, 0, sizeof(unsigned int), stream);
  kA<<<NBLK, BLK, 0, stream>>>(inp, FR, C, W, out, flag);
  kB<<<NBLK, BLK, 0, stream>>>(WLi, Fired, flag, out);
}